// Round 9
// baseline (148.749 us; speedup 1.0000x reference)
//
#include <hip/hip_runtime.h>
#include <math.h>
#include <stdint.h>

#define N_SAMPLES 4096
#define S_DIM 512
#define A_DIM 16
#define ACT_DIM 20
#define E_DIM 64
#define M_DIM 320      // A*ACT
#define J_DIM 1216     // 1024 (W_h1) + 64 (W_b1) + 64 (W_hf) + 64 (W_v1)
#define JPAD 1280      // padded to 10 * 128 so staging never goes OOB

#define GRID_BLOCKS 320          // 32 n-blocks x 10 j-blocks for the GEMM phase
#define BLOCK_THREADS 256

#define LOG2E 1.44269504088896f
#define LN2   0.69314718055995f

using bf16x8  = __attribute__((ext_vector_type(8))) short;
using f32x4   = __attribute__((ext_vector_type(4))) float;
using ushort8 = __attribute__((ext_vector_type(8))) unsigned short;

__device__ __forceinline__ unsigned short f2bf(float x) {  // RNE f32 -> bf16
    uint32_t u = __float_as_uint(x);
    u += 0x7fffu + ((u >> 16) & 1u);
    return (unsigned short)(u >> 16);
}
__device__ __forceinline__ float bf2f(unsigned short u) {
    return __uint_as_float(((uint32_t)u) << 16);
}

#define GL2L16(g, l) __builtin_amdgcn_global_load_lds(                        \
    (const __attribute__((address_space(1))) void*)(g),                      \
    (__attribute__((address_space(3))) void*)(l), 16, 0, 0)

// Manual grid barrier, R9 fix: SYSTEM-scope add+poll. R7/R8 post-mortem
// (unified theory): the fetch_add lands at the device coherence point, but an
// AGENT-scope poll load is served from the spinner's own XCD L2, which is NOT
// invalidated by other XCDs' atomics -> spinners read a stale counter until
// the line is naturally evicted (~50us/barrier). SYSTEM scope emits
// global_load sc0 sc1 (bypass L1+L2, read the coherence point) -> fresh value
// within ~1us. Data fences unchanged (they were already correct: R7/R8 passed).
// Co-residency: 320 blocks, 32KB LDS (5/CU), 64 VGPR, bounds(256,2) => >=512
// slots >= 320, so the spin cannot deadlock.
__device__ __forceinline__ void grid_barrier(unsigned int* c) {
    __syncthreads();
    if (threadIdx.x == 0) {
        __threadfence();   // release: this block's writes visible device-wide
        __hip_atomic_fetch_add(c, 1u, __ATOMIC_RELAXED, __HIP_MEMORY_SCOPE_SYSTEM);
        while (__hip_atomic_load(c, __ATOMIC_RELAXED, __HIP_MEMORY_SCOPE_SYSTEM)
               < (unsigned)GRID_BLOCKS)
            __builtin_amdgcn_s_sleep(8);
        __threadfence();   // acquire once: drop stale cached lines before reads
    }
    __syncthreads();
}

// LDS: GEMM tiles and mixer slots share one 32 KB union.
struct GemmLds {
    short As[2 * 128 * 32];   // 16 KB
    short Bs[2 * 128 * 32];   // 16 KB
};
struct WaveLds {
    float w1f[A_DIM][68];
    float qrow[M_DIM];
    float bd2[E_DIM];       // (base + b1) * log2e
    float wfl[E_DIM];       // wf * ln2
    float wfe[E_DIM];       // wf
    float qts[A_DIM];
};
union FusedLds {
    GemmLds g;
    WaveLds L[4];
};

__global__ __launch_bounds__(BLOCK_THREADS, 2) void qmix_fused(
    const float* __restrict__ q_agents, const int* __restrict__ actions,
    const float* __restrict__ Sf,
    const float* __restrict__ Wh1, const float* __restrict__ bh1,
    const float* __restrict__ Wb1, const float* __restrict__ bb1,
    const float* __restrict__ Whf, const float* __restrict__ bhf,
    const float* __restrict__ Wv1, const float* __restrict__ bv1,
    const float* __restrict__ Wv2, const float* __restrict__ bv2,
    float* __restrict__ out,
    unsigned short* __restrict__ Abf, unsigned short* __restrict__ Bbf,
    unsigned short* __restrict__ w1_bf,
    float* __restrict__ b1_all, float* __restrict__ wf_all,
    float* __restrict__ hv_all,
    unsigned int* bar)
{
    __shared__ FusedLds U;

    const int tid  = threadIdx.x;
    const int lane = tid & 63;
    const int wave = tid >> 6;

    // ============================ phase 1: f32 -> bf16 conversion ===========
    {
        const int A_QUADS = N_SAMPLES * S_DIM / 4;   // 524288
        const int B_QUADS = JPAD * S_DIM / 4;        // 163840
        const int STRIDE  = GRID_BLOCKS * BLOCK_THREADS;  // 81920
        for (int idx = blockIdx.x * BLOCK_THREADS + tid;
             idx < A_QUADS + B_QUADS; idx += STRIDE) {
            if (idx < A_QUADS) {
                float4 v = reinterpret_cast<const float4*>(Sf)[idx];
                ushort4 o = { f2bf(v.x), f2bf(v.y), f2bf(v.z), f2bf(v.w) };
                reinterpret_cast<ushort4*>(Abf)[idx] = o;
            } else {
                int q   = idx - A_QUADS;
                int row = q >> 7;
                int qc  = q & 127;
                ushort4 o = {0, 0, 0, 0};
                const float* src = nullptr;
                if (row < 1024)      src = Wh1 + (size_t)row * S_DIM;
                else if (row < 1088) src = Wb1 + (size_t)(row - 1024) * S_DIM;
                else if (row < 1152) src = Whf + (size_t)(row - 1088) * S_DIM;
                else if (row < 1216) src = Wv1 + (size_t)(row - 1152) * S_DIM;
                if (src) {
                    float4 v = reinterpret_cast<const float4*>(src)[qc];
                    o = ushort4{ f2bf(v.x), f2bf(v.y), f2bf(v.z), f2bf(v.w) };
                }
                reinterpret_cast<ushort4*>(Bbf)[q] = o;
            }
        }
    }

    grid_barrier(&bar[0]);

    // ============================ phase 2: MFMA GEMM =========================
    // Round-4 measured structure: BM=128 x BN=128, BK=32, dbuf,
    // STAGE(next) before COMPUTE(cur), one __syncthreads per k-step.
    {
        const int n0 = (blockIdx.x & 31) * 128;   // 32 n-blocks
        const int j0 = (blockIdx.x >> 5) * 128;   // 10 j-blocks

        const int gchunk = (lane & 3) ^ ((lane >> 3) & 3);
        const int srow   = wave * 32 + (lane >> 2);
        const unsigned short* gA0 = Abf + (size_t)(n0 + srow) * S_DIM + gchunk * 8;
        const unsigned short* gA1 = gA0 + 16 * S_DIM;
        const unsigned short* gB0 = Bbf + (size_t)(j0 + srow) * S_DIM + gchunk * 8;
        const unsigned short* gB1 = gB0 + 16 * S_DIM;
        short* lA0 = &U.g.As[(wave * 32) * 32];
        short* lA1 = &U.g.As[(wave * 32 + 16) * 32];
        short* lB0 = &U.g.Bs[(wave * 32) * 32];
        short* lB1 = &U.g.Bs[(wave * 32 + 16) * 32];

        const int wr = wave >> 1, wc = wave & 1;
        const int l16 = lane & 15, lk = lane >> 4;
        const int rchunk = lk ^ ((l16 >> 1) & 3);
        const short* pA = &U.g.As[(wr * 64 + l16) * 32 + rchunk * 8];
        const short* pB = &U.g.Bs[(wc * 64 + l16) * 32 + rchunk * 8];

        f32x4 acc[4][4] = {};

#define STAGE(bi, t) do {                                                     \
        GL2L16(gA0 + (size_t)(t) * 32, lA0 + (bi) * 4096);                    \
        GL2L16(gA1 + (size_t)(t) * 32, lA1 + (bi) * 4096);                    \
        GL2L16(gB0 + (size_t)(t) * 32, lB0 + (bi) * 4096);                    \
        GL2L16(gB1 + (size_t)(t) * 32, lB1 + (bi) * 4096);                    \
    } while (0)

#define COMPUTE(bi) do {                                                      \
        bf16x8 a_[4], b_[4];                                                  \
        _Pragma("unroll")                                                     \
        for (int m = 0; m < 4; ++m)                                           \
            a_[m] = *reinterpret_cast<const bf16x8*>(pA + (bi) * 4096 + m * 512); \
        _Pragma("unroll")                                                     \
        for (int n = 0; n < 4; ++n)                                           \
            b_[n] = *reinterpret_cast<const bf16x8*>(pB + (bi) * 4096 + n * 512); \
        __builtin_amdgcn_s_setprio(1);                                        \
        _Pragma("unroll")                                                     \
        for (int m = 0; m < 4; ++m)                                           \
            _Pragma("unroll")                                                 \
            for (int n = 0; n < 4; ++n)                                       \
                acc[m][n] = __builtin_amdgcn_mfma_f32_16x16x32_bf16(          \
                    a_[m], b_[n], acc[m][n], 0, 0, 0);                        \
        __builtin_amdgcn_s_setprio(0);                                        \
    } while (0)

        STAGE(0, 0);
        __syncthreads();
#pragma unroll 1
        for (int ks = 0; ks < 16; ks += 2) {
            STAGE(1, ks + 1);
            COMPUTE(0);
            __syncthreads();
            if (ks + 2 < 16) STAGE(0, ks + 2);
            COMPUTE(1);
            __syncthreads();
        }
#undef STAGE
#undef COMPUTE

        const int orow = n0 + wr * 64 + lk * 4;
        const int ocol = j0 + wc * 64 + l16;
#pragma unroll
        for (int m = 0; m < 4; ++m) {
#pragma unroll
            for (int n = 0; n < 4; ++n) {
                int j = ocol + n * 16;
#pragma unroll
                for (int r = 0; r < 4; ++r) {
                    int row = orow + m * 16 + r;
                    float val = acc[m][n][r];
                    if (j < 1024)
                        w1_bf[(size_t)row * 1024 + j] = f2bf(val + bh1[j]);
                    else if (j < 1088)
                        b1_all[(size_t)row * 64 + (j - 1024)] = val + bb1[j - 1024];
                    else if (j < 1152)
                        wf_all[(size_t)row * 64 + (j - 1088)] = val + bhf[j - 1088];
                    else if (j < J_DIM)
                        hv_all[(size_t)row * 64 + (j - 1152)] = val + bv1[j - 1152];
                }
            }
        }
    }

    grid_barrier(&bar[32]);   // second counter on its own cacheline

    // ============================ phase 3: mixer =============================
    // 1 wave per sample, grid-strided (1280 wave-slots for 4096 samples).
    // Trip counts uniform within a block (slot boundary 256 = block 64).
    {
        const int w = wave, l = lane;
        WaveLds& Q = U.L[w];
        for (int n = blockIdx.x * 4 + w; n < N_SAMPLES; n += GRID_BLOCKS * 4) {
#pragma unroll
            for (int j = 0; j < 5; ++j)
                Q.qrow[l + 64 * j] = q_agents[(size_t)n * M_DIM + l + 64 * j];
            float b1e  = b1_all[(size_t)n * 64 + l];
            float wfe_ = wf_all[(size_t)n * 64 + l];
            float hve  = hv_all[(size_t)n * 64 + l];
            float wv2e = Wv2[l];
            ushort8 u0 = *reinterpret_cast<const ushort8*>(w1_bf + (size_t)n * 1024 + l * 16);
            ushort8 u1 = *reinterpret_cast<const ushort8*>(w1_bf + (size_t)n * 1024 + l * 16 + 8);
            {
                int a = l >> 2, c0 = (l & 3) * 16;
#pragma unroll
                for (int q = 0; q < 8; ++q) Q.w1f[a][c0 + q]     = bf2f((unsigned short)u0[q]);
#pragma unroll
                for (int q = 0; q < 8; ++q) Q.w1f[a][c0 + 8 + q] = bf2f((unsigned short)u1[q]);
            }
            int act = (l < A_DIM) ? actions[n * A_DIM + l] : 0;
            __syncthreads();
            if (l < A_DIM) Q.qts[l] = Q.qrow[l * ACT_DIM + act];
            __syncthreads();

            float vp = fmaxf(hve, 0.f) * wv2e;
            float sw = wfe_;
#pragma unroll
            for (int off = 32; off; off >>= 1) {
                vp += __shfl_xor(vp, off, 64);
                sw += __shfl_xor(sw, off, 64);
            }
            float vfin = vp + bv2[0];

            float base = 0.f;
#pragma unroll
            for (int a = 0; a < A_DIM; ++a) base = fmaf(Q.qts[a], Q.w1f[a][l], base);
            Q.bd2[l] = (base + b1e) * LOG2E;
            Q.wfl[l] = wfe_ * LN2;
            Q.wfe[l] = wfe_;
            __syncthreads();

            const int i = l >> 2;
            const float qti = Q.qts[i];
            float d2[5];
#pragma unroll
            for (int k = 0; k < 5; ++k)
                d2[k] = (Q.qrow[i * ACT_DIM + 5 * (l & 3) + k] - qti) * LOG2E;

            float a1[5] = {0, 0, 0, 0, 0}, a2[5] = {0, 0, 0, 0, 0};
#pragma unroll 2
            for (int e0 = 0; e0 < E_DIM; e0 += 4) {
                f32x4 w4 = *reinterpret_cast<const f32x4*>(&Q.w1f[i][e0]);
                f32x4 b4 = *reinterpret_cast<const f32x4*>(&Q.bd2[e0]);
                f32x4 l4 = *reinterpret_cast<const f32x4*>(&Q.wfl[e0]);
                f32x4 f4 = *reinterpret_cast<const f32x4*>(&Q.wfe[e0]);
#pragma unroll
                for (int j = 0; j < 4; ++j) {
#pragma unroll
                    for (int k = 0; k < 5; ++k) {
                        float pre2 = fmaf(d2[k], w4[j], b4[j]);
                        a1[k] = fmaf(fmaxf(pre2, 0.f), l4[j], a1[k]);
                        a2[k] = fmaf(exp2f(fminf(pre2, 0.f)), f4[j], a2[k]);
                    }
                }
            }
#pragma unroll
            for (int k = 0; k < 5; ++k)
                out[(size_t)n * M_DIM + 5 * l + k] = a1[k] + a2[k] - sw + vfin;
            __syncthreads();   // protect LDS slot reuse across grid-stride iters
        }
    }
}

extern "C" void kernel_launch(void* const* d_in, const int* in_sizes, int n_in,
                              void* d_out, int out_size, void* d_ws, size_t ws_size,
                              hipStream_t stream)
{
    const float* q_agents = (const float*)d_in[0];
    const int*   actions  = (const int*)d_in[1];
    const float* state    = (const float*)d_in[2];
    const float* Wh1 = (const float*)d_in[3];
    const float* bh1 = (const float*)d_in[4];
    const float* Wb1 = (const float*)d_in[5];
    const float* bb1 = (const float*)d_in[6];
    const float* Whf = (const float*)d_in[7];
    const float* bhf = (const float*)d_in[8];
    const float* Wv1 = (const float*)d_in[9];
    const float* bv1 = (const float*)d_in[10];
    const float* Wv2 = (const float*)d_in[11];
    const float* bv2 = (const float*)d_in[12];
    float* out = (float*)d_out;

    char* ws = (char*)d_ws;
    unsigned short* Abf   = (unsigned short*)ws;                 // 4096*512*2 = 4 MB
    unsigned short* Bbf   = (unsigned short*)(ws + 4194304);     // 1280*512*2 = 1.31 MB
    unsigned short* w1_bf = (unsigned short*)(ws + 5505024);     // 4096*1024*2 = 8 MB
    float* b1_all = (float*)(ws + 5505024 + 8388608);            // 4096*64*4 = 1 MB
    float* wf_all = b1_all + (size_t)N_SAMPLES * 64;
    float* hv_all = wf_all + (size_t)N_SAMPLES * 64;
    unsigned int* bar = (unsigned int*)(ws + 20971520);          // 2 counters, 128B apart

    // zero the barrier counters on-stream (graph-capture legal, deterministic)
    hipMemsetAsync((void*)bar, 0, 33 * sizeof(unsigned int), stream);

    hipLaunchKernelGGL(qmix_fused, dim3(GRID_BLOCKS), dim3(BLOCK_THREADS), 0, stream,
                       q_agents, actions, state,
                       Wh1, bh1, Wb1, bb1, Whf, bhf, Wv1, bv1, Wv2, bv2,
                       out, Abf, Bbf, w1_bf, b1_all, wf_all, hv_all, bar);
}

// Round 10
// 62.664 us; speedup vs baseline: 2.3737x; 2.3737x over previous
//
#include <hip/hip_runtime.h>
#include <math.h>
#include <stdint.h>

#define N_SAMPLES 4096
#define S_DIM 512
#define A_DIM 16
#define ACT_DIM 20
#define E_DIM 64
#define M_DIM 320      // A*ACT
#define J_DIM 1216     // 1024 (W_h1) + 64 (W_b1) + 64 (W_hf) + 64 (W_v1)
#define JPAD 1280      // padded to 10 * 128 so staging never goes OOB

#define LOG2E 1.44269504088896f
#define LN2   0.69314718055995f

using bf16x8  = __attribute__((ext_vector_type(8))) short;
using f32x4   = __attribute__((ext_vector_type(4))) float;
using ushort8 = __attribute__((ext_vector_type(8))) unsigned short;

__device__ __forceinline__ unsigned short f2bf(float x) {  // RNE f32 -> bf16
    uint32_t u = __float_as_uint(x);
    u += 0x7fffu + ((u >> 16) & 1u);
    return (unsigned short)(u >> 16);
}
__device__ __forceinline__ float bf2f(unsigned short u) {
    return __uint_as_float(((uint32_t)u) << 16);
}

// ---------------------------------------------------------------- K0: convert
// Abf[4096][512] <- state ; Bbf[1280][512] <- {Wh1,Wb1,Whf,Wv1, zeros}
__global__ __launch_bounds__(256) void cvt_bf16(
    const float* __restrict__ S,
    const float* __restrict__ Wh1, const float* __restrict__ Wb1,
    const float* __restrict__ Whf, const float* __restrict__ Wv1,
    unsigned short* __restrict__ Abf, unsigned short* __restrict__ Bbf)
{
    const int A_QUADS = N_SAMPLES * S_DIM / 4;   // 524288
    const int B_QUADS = JPAD * S_DIM / 4;        // 163840
    int idx = blockIdx.x * 256 + threadIdx.x;
    if (idx < A_QUADS) {
        float4 v = reinterpret_cast<const float4*>(S)[idx];
        ushort4 o = { f2bf(v.x), f2bf(v.y), f2bf(v.z), f2bf(v.w) };
        reinterpret_cast<ushort4*>(Abf)[idx] = o;
    } else if (idx < A_QUADS + B_QUADS) {
        int q   = idx - A_QUADS;
        int row = q >> 7;          // 128 quads per 512-elem row
        int qc  = q & 127;
        ushort4 o = {0, 0, 0, 0};
        const float* src = nullptr;
        if (row < 1024)      src = Wh1 + (size_t)row * S_DIM;
        else if (row < 1088) src = Wb1 + (size_t)(row - 1024) * S_DIM;
        else if (row < 1152) src = Whf + (size_t)(row - 1088) * S_DIM;
        else if (row < 1216) src = Wv1 + (size_t)(row - 1152) * S_DIM;
        if (src) {
            float4 v = reinterpret_cast<const float4*>(src)[qc];
            o = ushort4{ f2bf(v.x), f2bf(v.y), f2bf(v.z), f2bf(v.w) };
        }
        reinterpret_cast<ushort4*>(Bbf)[q] = o;
    }
}

// ---------------------------------------------------------------- K1: MFMA GEMM
// 128x128 tile, BK=32, T3+T4 pipeline: 4 LDS buffers, prefetch depth 3,
// counted s_waitcnt vmcnt(8) + raw s_barrier (never drain to 0 in the loop).
// Fully unrolled 16 k-steps -> all vmcnt immediates & buffer idx compile-time.
#define GL2L16(g, l) __builtin_amdgcn_global_load_lds(                        \
    (const __attribute__((address_space(1))) void*)(g),                      \
    (__attribute__((address_space(3))) void*)(l), 16, 0, 0)

__global__ __launch_bounds__(256, 2) void gemm_bf16(
    const unsigned short* __restrict__ Abf,
    const unsigned short* __restrict__ Bbf,
    const float* __restrict__ bh1, const float* __restrict__ bb1,
    const float* __restrict__ bhf, const float* __restrict__ bv1,
    unsigned short* __restrict__ w1_bf,
    float* __restrict__ b1_all, float* __restrict__ wf_all,
    float* __restrict__ hv_all)
{
    // 4 buffers x [128][32] shorts, buffer stride 4096 shorts = 8 KB
    __shared__ short As[4 * 4096];   // 32 KB
    __shared__ short Bs[4 * 4096];   // 32 KB

    const int tid  = threadIdx.x;
    const int lane = tid & 63;
    const int wave = tid >> 6;
    const int n0 = blockIdx.x * 128;
    const int j0 = blockIdx.y * 128;

    // staging (verified R2/R4, conflicts=0): LDS[row][c] holds global chunk
    // c ^ ((local_row>>1)&3); source pre-swizzled, LDS dest linear.
    const int gchunk = (lane & 3) ^ ((lane >> 3) & 3);
    const int srow   = wave * 32 + (lane >> 2);
    const unsigned short* gA0 = Abf + (size_t)(n0 + srow) * S_DIM + gchunk * 8;
    const unsigned short* gA1 = gA0 + 16 * S_DIM;
    const unsigned short* gB0 = Bbf + (size_t)(j0 + srow) * S_DIM + gchunk * 8;
    const unsigned short* gB1 = gB0 + 16 * S_DIM;
    short* lA0 = &As[(wave * 32) * 32];
    short* lA1 = &As[(wave * 32 + 16) * 32];
    short* lB0 = &Bs[(wave * 32) * 32];
    short* lB1 = &Bs[(wave * 32 + 16) * 32];

    // fragments: wave (wr,wc) owns 64x64; 4x4 16x16x32 frags
    const int wr = wave >> 1, wc = wave & 1;
    const int l16 = lane & 15, lk = lane >> 4;
    const int rchunk = lk ^ ((l16 >> 1) & 3);
    const short* pA = &As[(wr * 64 + l16) * 32 + rchunk * 8];
    const short* pB = &Bs[(wc * 64 + l16) * 32 + rchunk * 8];

    f32x4 acc[4][4] = {};

#define STAGE(bi, t) do {                                                     \
        GL2L16(gA0 + (size_t)(t) * 32, lA0 + (bi) * 4096);                    \
        GL2L16(gA1 + (size_t)(t) * 32, lA1 + (bi) * 4096);                    \
        GL2L16(gB0 + (size_t)(t) * 32, lB0 + (bi) * 4096);                    \
        GL2L16(gB1 + (size_t)(t) * 32, lB1 + (bi) * 4096);                    \
    } while (0)

#define COMPUTE(bi) do {                                                      \
        bf16x8 a_[4], b_[4];                                                  \
        _Pragma("unroll")                                                     \
        for (int m = 0; m < 4; ++m)                                           \
            a_[m] = *reinterpret_cast<const bf16x8*>(pA + (bi) * 4096 + m * 512); \
        _Pragma("unroll")                                                     \
        for (int n = 0; n < 4; ++n)                                           \
            b_[n] = *reinterpret_cast<const bf16x8*>(pB + (bi) * 4096 + n * 512); \
        __builtin_amdgcn_s_setprio(1);                                        \
        _Pragma("unroll")                                                     \
        for (int m = 0; m < 4; ++m)                                           \
            _Pragma("unroll")                                                 \
            for (int n = 0; n < 4; ++n)                                       \
                acc[m][n] = __builtin_amdgcn_mfma_f32_16x16x32_bf16(          \
                    a_[m], b_[n], acc[m][n], 0, 0, 0);                        \
        __builtin_amdgcn_s_setprio(0);                                        \
    } while (0)

    // KSTEP(T): wait tile T's 4 loads (counted, leaves deeper prefetch in
    // flight), barrier, then (optionally) stage tile T+3 into buf (T+3)&3 --
    // that buffer was last read by COMPUTE(T-1), finished before this barrier.
#define KSTEP(T, VM, DOSTAGE) do {                                            \
        asm volatile("s_waitcnt vmcnt(" #VM ")" ::: "memory");                \
        __builtin_amdgcn_sched_barrier(0);                                    \
        __builtin_amdgcn_s_barrier();                                         \
        __builtin_amdgcn_sched_barrier(0);                                    \
        if (DOSTAGE) STAGE(((T) + 3) & 3, (T) + 3);                           \
        COMPUTE((T) & 3);                                                     \
    } while (0)

    // prologue: 3 tiles in flight (12 loads)
    STAGE(0, 0);
    STAGE(1, 1);
    STAGE(2, 2);

    KSTEP(0, 8, 1);  KSTEP(1, 8, 1);  KSTEP(2, 8, 1);  KSTEP(3, 8, 1);
    KSTEP(4, 8, 1);  KSTEP(5, 8, 1);  KSTEP(6, 8, 1);  KSTEP(7, 8, 1);
    KSTEP(8, 8, 1);  KSTEP(9, 8, 1);  KSTEP(10, 8, 1); KSTEP(11, 8, 1);
    KSTEP(12, 8, 1); KSTEP(13, 8, 0); KSTEP(14, 4, 0); KSTEP(15, 0, 0);

#undef KSTEP
#undef STAGE
#undef COMPUTE

    // epilogue: C/D layout col=lane&15, row=(lane>>4)*4+reg (m89-verified)
    const int orow = n0 + wr * 64 + lk * 4;
    const int ocol = j0 + wc * 64 + l16;
#pragma unroll
    for (int m = 0; m < 4; ++m) {
#pragma unroll
        for (int n = 0; n < 4; ++n) {
            int j = ocol + n * 16;
#pragma unroll
            for (int r = 0; r < 4; ++r) {
                int row = orow + m * 16 + r;
                float val = acc[m][n][r];
                if (j < 1024)
                    w1_bf[(size_t)row * 1024 + j] = f2bf(val + bh1[j]);
                else if (j < 1088)
                    b1_all[(size_t)row * 64 + (j - 1024)] = val + bb1[j - 1024];
                else if (j < 1152)
                    wf_all[(size_t)row * 64 + (j - 1088)] = val + bhf[j - 1088];
                else if (j < J_DIM)
                    hv_all[(size_t)row * 64 + (j - 1152)] = val + bv1[j - 1152];
            }
        }
    }
}

// ---------------------------------------------------------------- K2: mixer
// R4 structure (measured-good): 1 wave/sample, lane owns 5 m's sharing agent
// i = l>>2; branchless elu via exp2 with log2e folded into delta/bias.
struct WaveLds {
    float w1f[A_DIM][68];
    float qrow[M_DIM];
    float bd2[E_DIM];       // (base + b1) * log2e
    float wfl[E_DIM];       // wf * ln2
    float wfe[E_DIM];       // wf
    float qts[A_DIM];
};

__global__ __launch_bounds__(256) void mixer(
    const float* __restrict__ q_agents, const int* __restrict__ actions,
    const unsigned short* __restrict__ w1_bf, const float* __restrict__ b1_all,
    const float* __restrict__ wf_all, const float* __restrict__ hv_all,
    const float* __restrict__ Wv2, const float* __restrict__ bv2,
    float* __restrict__ out)
{
    __shared__ WaveLds L[4];
    const int w = threadIdx.x >> 6;
    const int l = threadIdx.x & 63;
    const int n = blockIdx.x * 4 + w;
    WaveLds& Q = L[w];

#pragma unroll
    for (int j = 0; j < 5; ++j)
        Q.qrow[l + 64 * j] = q_agents[(size_t)n * M_DIM + l + 64 * j];
    float b1e  = b1_all[(size_t)n * 64 + l];
    float wfe_ = wf_all[(size_t)n * 64 + l];
    float hve  = hv_all[(size_t)n * 64 + l];
    float wv2e = Wv2[l];
    ushort8 u0 = *reinterpret_cast<const ushort8*>(w1_bf + (size_t)n * 1024 + l * 16);
    ushort8 u1 = *reinterpret_cast<const ushort8*>(w1_bf + (size_t)n * 1024 + l * 16 + 8);
    {
        int a = l >> 2, c0 = (l & 3) * 16;
#pragma unroll
        for (int q = 0; q < 8; ++q) Q.w1f[a][c0 + q]     = bf2f((unsigned short)u0[q]);
#pragma unroll
        for (int q = 0; q < 8; ++q) Q.w1f[a][c0 + 8 + q] = bf2f((unsigned short)u1[q]);
    }
    int act = (l < A_DIM) ? actions[n * A_DIM + l] : 0;
    __syncthreads();
    if (l < A_DIM) Q.qts[l] = Q.qrow[l * ACT_DIM + act];
    __syncthreads();

    float vp = fmaxf(hve, 0.f) * wv2e;
    float sw = wfe_;
#pragma unroll
    for (int off = 32; off; off >>= 1) {
        vp += __shfl_xor(vp, off, 64);
        sw += __shfl_xor(sw, off, 64);
    }
    float vfin = vp + bv2[0];

    float base = 0.f;
#pragma unroll
    for (int a = 0; a < A_DIM; ++a) base = fmaf(Q.qts[a], Q.w1f[a][l], base);
    Q.bd2[l] = (base + b1e) * LOG2E;
    Q.wfl[l] = wfe_ * LN2;
    Q.wfe[l] = wfe_;
    __syncthreads();

    const int i = l >> 2;
    const float qti = Q.qts[i];
    float d2[5];
#pragma unroll
    for (int k = 0; k < 5; ++k)
        d2[k] = (Q.qrow[i * ACT_DIM + 5 * (l & 3) + k] - qti) * LOG2E;

    float a1[5] = {0, 0, 0, 0, 0}, a2[5] = {0, 0, 0, 0, 0};
#pragma unroll 2
    for (int e0 = 0; e0 < E_DIM; e0 += 4) {
        f32x4 w4 = *reinterpret_cast<const f32x4*>(&Q.w1f[i][e0]);
        f32x4 b4 = *reinterpret_cast<const f32x4*>(&Q.bd2[e0]);
        f32x4 l4 = *reinterpret_cast<const f32x4*>(&Q.wfl[e0]);
        f32x4 f4 = *reinterpret_cast<const f32x4*>(&Q.wfe[e0]);
#pragma unroll
        for (int j = 0; j < 4; ++j) {
#pragma unroll
            for (int k = 0; k < 5; ++k) {
                float pre2 = fmaf(d2[k], w4[j], b4[j]);
                a1[k] = fmaf(fmaxf(pre2, 0.f), l4[j], a1[k]);
                a2[k] = fmaf(exp2f(fminf(pre2, 0.f)), f4[j], a2[k]);
            }
        }
    }
#pragma unroll
    for (int k = 0; k < 5; ++k)
        out[(size_t)n * M_DIM + 5 * l + k] = a1[k] + a2[k] - sw + vfin;
}

extern "C" void kernel_launch(void* const* d_in, const int* in_sizes, int n_in,
                              void* d_out, int out_size, void* d_ws, size_t ws_size,
                              hipStream_t stream)
{
    const float* q_agents = (const float*)d_in[0];
    const int*   actions  = (const int*)d_in[1];
    const float* state    = (const float*)d_in[2];
    const float* Wh1 = (const float*)d_in[3];
    const float* bh1 = (const float*)d_in[4];
    const float* Wb1 = (const float*)d_in[5];
    const float* bb1 = (const float*)d_in[6];
    const float* Whf = (const float*)d_in[7];
    const float* bhf = (const float*)d_in[8];
    const float* Wv1 = (const float*)d_in[9];
    const float* bv1 = (const float*)d_in[10];
    const float* Wv2 = (const float*)d_in[11];
    const float* bv2 = (const float*)d_in[12];
    float* out = (float*)d_out;

    char* ws = (char*)d_ws;
    unsigned short* Abf   = (unsigned short*)ws;                 // 4096*512*2 = 4 MB
    unsigned short* Bbf   = (unsigned short*)(ws + 4194304);     // 1280*512*2 = 1.31 MB
    unsigned short* w1_bf = (unsigned short*)(ws + 5505024);     // 4096*1024*2 = 8 MB
    float* b1_all = (float*)(ws + 5505024 + 8388608);            // 4096*64*4 = 1 MB
    float* wf_all = b1_all + (size_t)N_SAMPLES * 64;
    float* hv_all = wf_all + (size_t)N_SAMPLES * 64;

    const int total_quads = N_SAMPLES * S_DIM / 4 + JPAD * S_DIM / 4;   // 688128
    hipLaunchKernelGGL(cvt_bf16, dim3((total_quads + 255) / 256), dim3(256), 0, stream,
                       state, Wh1, Wb1, Whf, Wv1, Abf, Bbf);

    dim3 g1(N_SAMPLES / 128, JPAD / 128);                        // 32 x 10
    hipLaunchKernelGGL(gemm_bf16, g1, dim3(256), 0, stream,
                       Abf, Bbf, bh1, bb1, bhf, bv1,
                       w1_bf, b1_all, wf_all, hv_all);

    hipLaunchKernelGGL(mixer, dim3(N_SAMPLES / 4), dim3(256), 0, stream,
                       q_agents, actions, w1_bf, b1_all, wf_all, hv_all,
                       Wv2, bv2, out);
}